// Round 10
// baseline (148.066 us; speedup 1.0000x reference)
//
#include <hip/hip_runtime.h>
#include <math.h>

#define C_DIM 1000
#define BIG   1.0e30f   // pad: u huge -> rcp underflows -> 0 in every sum (self-masking)

typedef __attribute__((ext_vector_type(4))) float f32x4;

__device__ __forceinline__ float fexp2(float x) { return __builtin_amdgcn_exp2f(x); }
__device__ __forceinline__ float flog2(float x) { return __builtin_amdgcn_logf(x); }
__device__ __forceinline__ float frcp(float x)  { return __builtin_amdgcn_rcpf(x); }

// ---- DPP wave64 reduction primitives (VALU pipe) ----
template <int CTRL, int RM>
__device__ __forceinline__ float dpp_add_term(float x) {
    int y = __builtin_amdgcn_update_dpp(0, __float_as_int(x), CTRL, RM, 0xf, true);
    return __int_as_float(y);
}
template <int CTRL, int RM>
__device__ __forceinline__ float dpp_max_term(float x) {
    int y = __builtin_amdgcn_update_dpp(__float_as_int(x), __float_as_int(x), CTRL, RM, 0xf, false);
    return __int_as_float(y);
}

// After this chain, lane 63 holds the wave total (no broadcast).
#define DPP_SUM_CHAIN(x)                      \
    x += dpp_add_term<0x111, 0xf>(x);         \
    x += dpp_add_term<0x112, 0xf>(x);         \
    x += dpp_add_term<0x114, 0xf>(x);         \
    x += dpp_add_term<0x118, 0xf>(x);         \
    x += dpp_add_term<0x142, 0xa>(x);         \
    x += dpp_add_term<0x143, 0xc>(x);

#define DPP_MAX_CHAIN(x)                                  \
    x = fmaxf(x, dpp_max_term<0x111, 0xf>(x));            \
    x = fmaxf(x, dpp_max_term<0x112, 0xf>(x));            \
    x = fmaxf(x, dpp_max_term<0x114, 0xf>(x));            \
    x = fmaxf(x, dpp_max_term<0x118, 0xf>(x));            \
    x = fmaxf(x, dpp_max_term<0x142, 0xa>(x));            \
    x = fmaxf(x, dpp_max_term<0x143, 0xc>(x));

__device__ __forceinline__ float bcast63(float x) {
    return __int_as_float(__builtin_amdgcn_readlane(__float_as_int(x), 63));
}

#define GLOAD(dst, addr) \
    asm volatile("global_load_dwordx4 %0, %1, off" : "=v"(dst) : "v"(addr))

// One wave = 2 rows, fully interleaved (2x ILP on every dependent chain).
// Grid 2048 blocks x 4 waves = 8192 waves: single generation, no turnover.
__global__ __launch_bounds__(256) void btll(
    const float* __restrict__ inputs, const float* __restrict__ targets,
    float* __restrict__ row_out, int n_rows,
    float C0, float E_off, float dE)
{
    const int lane = threadIdx.x & 63;
    const int wave = threadIdx.x >> 6;
    const int wid  = blockIdx.x * 4 + wave;
    const int rA   = wid * 2;
    if (rA >= n_rows) return;
    const int rB   = (rA + 1 < n_rows) ? rA + 1 : rA;

    const float* pA = inputs + (size_t)rA * C_DIM;
    const float* pB = inputs + (size_t)rB * C_DIM;
    const int o0 = lane << 2;                      // 16B-aligned float offsets
    const int o1 = o0 + 256;
    const int o2 = o0 + 512;
    const bool m3 = (o0 + 768) < 1000;             // lanes 58..63 are dup/pad
    const int o3 = m3 ? o0 + 768 : 996;            // clamp keeps addr in-bounds

    // ---- inputs for both rows: 8 loads all in flight, one wait ----
    f32x4 xA0, xA1, xA2, xA3, xB0, xB1, xB2, xB3;
    GLOAD(xA0, pA + o0); GLOAD(xA1, pA + o1); GLOAD(xA2, pA + o2); GLOAD(xA3, pA + o3);
    GLOAD(xB0, pB + o0); GLOAD(xB1, pB + o1); GLOAD(xB2, pB + o2); GLOAD(xB3, pB + o3);
    asm volatile("s_waitcnt vmcnt(0)"
                 : "+v"(xA0), "+v"(xA1), "+v"(xA2), "+v"(xA3),
                   "+v"(xB0), "+v"(xB1), "+v"(xB2), "+v"(xB3));

    // ---- targets issued now; latency hides under the whole solve ----
    const float* qA = targets + (size_t)rA * C_DIM;
    const float* qB = targets + (size_t)rB * C_DIM;
    f32x4 tA0, tA1, tA2, tA3, tB0, tB1, tB2, tB3;
    GLOAD(tA0, qA + o0); GLOAD(tA1, qA + o1); GLOAD(tA2, qA + o2); GLOAD(tA3, qA + o3);
    GLOAD(tB0, qB + o0); GLOAD(tB1, qB + o1); GLOAD(tB2, qB + o2); GLOAD(tB3, qB + o3);

    if (!m3) {
        xA3 = (f32x4){-BIG, -BIG, -BIG, -BIG};
        xB3 = (f32x4){-BIG, -BIG, -BIG, -BIG};
    }

    float aA[16], aB[16];
    aA[0]=xA0.x; aA[1]=xA0.y; aA[2]=xA0.z; aA[3]=xA0.w;
    aA[4]=xA1.x; aA[5]=xA1.y; aA[6]=xA1.z; aA[7]=xA1.w;
    aA[8]=xA2.x; aA[9]=xA2.y; aA[10]=xA2.z; aA[11]=xA2.w;
    aA[12]=xA3.x; aA[13]=xA3.y; aA[14]=xA3.z; aA[15]=xA3.w;
    aB[0]=xB0.x; aB[1]=xB0.y; aB[2]=xB0.z; aB[3]=xB0.w;
    aB[4]=xB1.x; aB[5]=xB1.y; aB[6]=xB1.z; aB[7]=xB1.w;
    aB[8]=xB2.x; aB[9]=xB2.y; aB[10]=xB2.z; aB[11]=xB2.w;
    aB[12]=xB3.x; aB[13]=xB3.y; aB[14]=xB3.z; aB[15]=xB3.w;

    // ---- row max (interleaved trees + interleaved DPP chains) ----
    float mA0 = fmaxf(fmaxf(aA[0], aA[1]),  fmaxf(aA[2], aA[3]));
    float mB0 = fmaxf(fmaxf(aB[0], aB[1]),  fmaxf(aB[2], aB[3]));
    float mA1 = fmaxf(fmaxf(aA[4], aA[5]),  fmaxf(aA[6], aA[7]));
    float mB1 = fmaxf(fmaxf(aB[4], aB[5]),  fmaxf(aB[6], aB[7]));
    float mA2 = fmaxf(fmaxf(aA[8], aA[9]),  fmaxf(aA[10], aA[11]));
    float mB2 = fmaxf(fmaxf(aB[8], aB[9]),  fmaxf(aB[10], aB[11]));
    float mA3 = fmaxf(fmaxf(aA[12], aA[13]), fmaxf(aA[14], aA[15]));
    float mB3 = fmaxf(fmaxf(aB[12], aB[13]), fmaxf(aB[14], aB[15]));
    float muA = fmaxf(fmaxf(mA0, mA1), fmaxf(mA2, mA3));
    float muB = fmaxf(fmaxf(mB0, mB1), fmaxf(mB2, mB3));
    DPP_MAX_CHAIN(muA)
    DPP_MAX_CHAIN(muB)
    muA = bcast63(muA);
    muB = bcast63(muB);

    float bA[16], bB[16];
    #pragma unroll
    for (int k = 0; k < 16; ++k) {
        bA[k] = -0.2f * (aA[k] - muA);   // >= 0; pad -> ~2e29
        bB[k] = -0.2f * (aB[k] - muB);
    }

    // ---- sweep 1: FP at lam=1 ----
    float sA = 0.0f, sB = 0.0f;
    #pragma unroll
    for (int k = 0; k < 16; ++k) {
        float uA = 1.0f + bA[k];
        float uB = 1.0f + bB[k];
        float uA2 = uA * uA, uB2 = uB * uB;
        sA += frcp(uA2 * uA2 * uA);
        sB += frcp(uB2 * uB2 * uB);
    }
    DPP_SUM_CHAIN(sA)
    DPP_SUM_CHAIN(sB)
    const float lamA = fexp2(-0.2f * flog2(bcast63(sA)));
    const float lamB = fexp2(-0.2f * flog2(bcast63(sB)));

    // ---- sweep 2: FP at lam -> w0 (below root; Newton-safe) ----
    sA = 0.0f; sB = 0.0f;
    #pragma unroll
    for (int k = 0; k < 16; ++k) {
        float uA = fmaf(lamA, bA[k], 1.0f);
        float uB = fmaf(lamB, bB[k], 1.0f);
        float uA2 = uA * uA, uB2 = uB * uB;
        sA += frcp(uA2 * uA2 * uA);
        sB += frcp(uB2 * uB2 * uB);
    }
    DPP_SUM_CHAIN(sA)
    DPP_SUM_CHAIN(sB)
    const float wA = fexp2(0.2f * flog2(bcast63(sA)));
    const float wB = fexp2(0.2f * flog2(bcast63(sB)));

    // ---- sweep 3: merged Newton + loss sums (2nd-order corrected) ----
    float S4A = 0.0f, S5A = 0.0f, S6A = 0.0f, S9A = 0.0f, S10A = 0.0f, S11A = 0.0f;
    float S4B = 0.0f, S5B = 0.0f, S6B = 0.0f, S9B = 0.0f, S10B = 0.0f, S11B = 0.0f;
    #pragma unroll
    for (int k = 0; k < 16; ++k) {
        float rA = frcp(wA + bA[k]);
        float rB = frcp(wB + bB[k]);
        float rA2 = rA * rA,   rB2 = rB * rB;
        float rA4 = rA2 * rA2, rB4 = rB2 * rB2;
        float rA5 = rA4 * rA,  rB5 = rB4 * rB;
        float rA9 = rA4 * rA5, rB9 = rB4 * rB5;
        S4A  += rA4;        S4B  += rB4;
        S5A  += rA5;        S5B  += rB5;
        S6A  += rA5 * rA;   S6B  += rB5 * rB;
        S9A  += rA9;        S9B  += rB9;
        S10A += rA5 * rA5;  S10B += rB5 * rB5;
        S11A += rA9 * rA2;  S11B += rB9 * rB2;
    }
    DPP_SUM_CHAIN(S4A)  DPP_SUM_CHAIN(S4B)
    DPP_SUM_CHAIN(S5A)  DPP_SUM_CHAIN(S5B)
    DPP_SUM_CHAIN(S6A)  DPP_SUM_CHAIN(S6B)
    DPP_SUM_CHAIN(S9A)  DPP_SUM_CHAIN(S9B)
    DPP_SUM_CHAIN(S10A) DPP_SUM_CHAIN(S10B)
    DPP_SUM_CHAIN(S11A) DPP_SUM_CHAIN(S11B)
    // NO broadcast: totals live on lane 63 only; final math runs redundantly.

    // ---- targets arrived long ago; hot-logit after solve ----
    asm volatile("s_waitcnt vmcnt(0)"
                 : "+v"(tA0), "+v"(tA1), "+v"(tA2), "+v"(tA3),
                   "+v"(tB0), "+v"(tB1), "+v"(tB2), "+v"(tB3));
    if (!m3) {
        tA3 = (f32x4){0.f, 0.f, 0.f, 0.f};
        tB3 = (f32x4){0.f, 0.f, 0.f, 0.f};
    }
    float hA0 = tA0.x * aA[0],  hA1 = tA0.y * aA[1],  hA2 = tA0.z * aA[2],  hA3 = tA0.w * aA[3];
    float hB0 = tB0.x * aB[0],  hB1 = tB0.y * aB[1],  hB2 = tB0.z * aB[2],  hB3 = tB0.w * aB[3];
    hA0 = fmaf(tA1.x, aA[4], hA0);  hA1 = fmaf(tA1.y, aA[5], hA1);
    hB0 = fmaf(tB1.x, aB[4], hB0);  hB1 = fmaf(tB1.y, aB[5], hB1);
    hA2 = fmaf(tA1.z, aA[6], hA2);  hA3 = fmaf(tA1.w, aA[7], hA3);
    hB2 = fmaf(tB1.z, aB[6], hB2);  hB3 = fmaf(tB1.w, aB[7], hB3);
    hA0 = fmaf(tA2.x, aA[8], hA0);  hA1 = fmaf(tA2.y, aA[9], hA1);
    hB0 = fmaf(tB2.x, aB[8], hB0);  hB1 = fmaf(tB2.y, aB[9], hB1);
    hA2 = fmaf(tA2.z, aA[10], hA2); hA3 = fmaf(tA2.w, aA[11], hA3);
    hB2 = fmaf(tB2.z, aB[10], hB2); hB3 = fmaf(tB2.w, aB[11], hB3);
    hA0 = fmaf(tA3.x, aA[12], hA0); hA1 = fmaf(tA3.y, aA[13], hA1);
    hB0 = fmaf(tB3.x, aB[12], hB0); hB1 = fmaf(tB3.y, aB[13], hB1);
    hA2 = fmaf(tA3.z, aA[14], hA2); hA3 = fmaf(tA3.w, aA[15], hA3);
    hB2 = fmaf(tB3.z, aB[14], hB2); hB3 = fmaf(tB3.w, aB[15], hB3);
    float ahA = (hA0 + hA1) + (hA2 + hA3);
    float ahB = (hB0 + hB1) + (hB2 + hB3);
    DPP_SUM_CHAIN(ahA)
    DPP_SUM_CHAIN(ahB)
    // ahA/ahB valid on lane 63 only.

    const float hbA = -0.2f * (ahA - muA);
    const float hbB = -0.2f * (ahB - muB);

    const float dA  = (S5A - 1.0f) * 0.2f * frcp(S6A);
    const float dB  = (S5B - 1.0f) * 0.2f * frcp(S6B);
    const float w1A = wA + dA,  d2A = dA * dA;
    const float w1B = wB + dB,  d2B = dB * dB;
    const float S4cA = S4A + fmaf(10.0f * d2A, S6A,  -4.0f * dA * S5A);
    const float S4cB = S4B + fmaf(10.0f * d2B, S6B,  -4.0f * dB * S5B);
    const float S9cA = S9A + fmaf(45.0f * d2A, S11A, -9.0f * dA * S10A);
    const float S9cB = S9B + fmaf(45.0f * d2B, S11B, -9.0f * dB * S10B);
    const float rhA  = frcp(w1A + hbA);
    const float rhB  = frcp(w1B + hbB);
    const float rhA2 = rhA * rhA, rhB2 = rhB * rhB;
    const float rhA4 = rhA2 * rhA2, rhB4 = rhB2 * rhB2;

    const float lossA = fmaf(-E_off, S4cA, fmaf(-dE, rhA4, fmaf(1.0f / 1.8f, S9cA, C0)));
    const float lossB = fmaf(-E_off, S4cB, fmaf(-dE, rhB4, fmaf(1.0f / 1.8f, S9cB, C0)));

    if (lane == 63) {
        row_out[rA] = lossA;
        if (rB != rA) row_out[rB] = lossB;
    }
}

__global__ __launch_bounds__(1024) void reduce_mean(
    const float* __restrict__ row_out, float* __restrict__ out, int n)
{
    __shared__ double sm[16];
    const int lane = threadIdx.x & 63;
    const int wv   = threadIdx.x >> 6;
    const float4* r4 = (const float4*)row_out;
    const int n4 = n >> 2;
    double s = 0.0;
    for (int i = threadIdx.x; i < n4; i += 1024) {
        float4 v = r4[i];
        s += (double)v.x + (double)v.y + (double)v.z + (double)v.w;
    }
    #pragma unroll
    for (int off = 32; off > 0; off >>= 1) s += __shfl_xor(s, off, 64);
    if (lane == 0) sm[wv] = s;
    __syncthreads();
    if (wv == 0) {
        double t = (lane < 16) ? sm[lane] : 0.0;
        #pragma unroll
        for (int off = 32; off > 0; off >>= 1) t += __shfl_xor(t, off, 64);
        if (lane == 0) out[0] = (float)(t / (double)n);
    }
}

extern "C" void kernel_launch(void* const* d_in, const int* in_sizes, int n_in,
                              void* d_out, int out_size, void* d_ws, size_t ws_size,
                              hipStream_t stream) {
    const float* inputs  = (const float*)d_in[0];
    const float* targets = (const float*)d_in[1];
    float* out = (float*)d_out;

    const int N = in_sizes[0] / C_DIM;
    float* row_out = (float*)d_ws;

    // Smoothed one-hot targets take 2 values; per-elem loss = F - E*r4 + r9/1.8.
    // Row sum = C0 - E_off*S4 - (E_on-E_off)*r4_hot + S9/1.8, C0 = 999*F_off + F_on.
    const double ls    = 0.05;
    const double c1g_d = 1.0 - (1000.0 / 999.0) * ls;
    const double c2_d  = ls / 999.0;
    const float  tp_on_f  = (float)c1g_d + (float)c2_d;
    const float  tp_off_f = (float)c2_d;
    const double tp_on  = (double)tp_on_f;
    const double tp_off = (double)tp_off_f;
    const double A_on  = (pow(tp_on  + 1e-8, 0.8) - 1.0) / 0.8;
    const double A_off = (pow(tp_off + 1e-8, 0.8) - 1.0) / 0.8;
    const double B_on  = pow(tp_on,  1.8);
    const double B_off = pow(tp_off, 1.8);
    const double E_on_d  = 1.25 * tp_on;
    const double E_off_d = 1.25 * tp_off;
    const double F_on_d  = tp_on  * A_on  + E_on_d  - B_on  / 1.8;
    const double F_off_d = tp_off * A_off + E_off_d - B_off / 1.8;
    const double C0_d    = (C_DIM - 1) * F_off_d + F_on_d;
    const double dE_d    = E_on_d - E_off_d;

    const int waves_needed = (N + 1) / 2;
    dim3 grid((waves_needed + 3) / 4);
    btll<<<grid, 256, 0, stream>>>(inputs, targets, row_out, N,
                                   (float)C0_d, (float)E_off_d, (float)dE_d);
    reduce_mean<<<1, 1024, 0, stream>>>(row_out, out, N);
}

// Round 11
// 147.202 us; speedup vs baseline: 1.0059x; 1.0059x over previous
//
#include <hip/hip_runtime.h>
#include <math.h>

#define C_DIM 1000
#define ROWS  4          // rows per wave, software-pipelined depth-1
#define BIG   1.0e30f    // pad: u huge -> rcp underflows -> 0 in every sum

typedef __attribute__((ext_vector_type(4))) float f32x4;

__device__ __forceinline__ float fexp2(float x) { return __builtin_amdgcn_exp2f(x); }
__device__ __forceinline__ float flog2(float x) { return __builtin_amdgcn_logf(x); }
__device__ __forceinline__ float frcp(float x)  { return __builtin_amdgcn_rcpf(x); }

// ---- DPP wave64 reductions (VALU pipe). After chain, lane 63 holds total. ----
template <int CTRL, int RM>
__device__ __forceinline__ float dpp_add_term(float x) {
    int y = __builtin_amdgcn_update_dpp(0, __float_as_int(x), CTRL, RM, 0xf, true);
    return __int_as_float(y);
}
template <int CTRL, int RM>
__device__ __forceinline__ float dpp_max_term(float x) {
    int y = __builtin_amdgcn_update_dpp(__float_as_int(x), __float_as_int(x), CTRL, RM, 0xf, false);
    return __int_as_float(y);
}

#define DPP_SUM_CHAIN(x)                      \
    x += dpp_add_term<0x111, 0xf>(x);         \
    x += dpp_add_term<0x112, 0xf>(x);         \
    x += dpp_add_term<0x114, 0xf>(x);         \
    x += dpp_add_term<0x118, 0xf>(x);         \
    x += dpp_add_term<0x142, 0xa>(x);         \
    x += dpp_add_term<0x143, 0xc>(x);

#define DPP_MAX_CHAIN(x)                                  \
    x = fmaxf(x, dpp_max_term<0x111, 0xf>(x));            \
    x = fmaxf(x, dpp_max_term<0x112, 0xf>(x));            \
    x = fmaxf(x, dpp_max_term<0x114, 0xf>(x));            \
    x = fmaxf(x, dpp_max_term<0x118, 0xf>(x));            \
    x = fmaxf(x, dpp_max_term<0x142, 0xa>(x));            \
    x = fmaxf(x, dpp_max_term<0x143, 0xc>(x));

__device__ __forceinline__ float bcast63(float x) {
    return __int_as_float(__builtin_amdgcn_readlane(__float_as_int(x), 63));
}

#define GLOAD(dst, addr) \
    asm volatile("global_load_dwordx4 %0, %1, off" : "=v"(dst) : "v"(addr))

// Wait until at most N of this wave's global loads remain outstanding; the
// listed registers (current row's 8 loads, issued before the newer 8) are
// then valid. vmcnt completion is in issue order (m135).
#define WAIT_CUR(Nstr, A0, A1, A2, A3, B0, B1, B2, B3)              \
    asm volatile("s_waitcnt vmcnt(" Nstr ")"                        \
                 : "+v"(A0), "+v"(A1), "+v"(A2), "+v"(A3),          \
                   "+v"(B0), "+v"(B1), "+v"(B2), "+v"(B3))

// One wave = ROWS consecutive rows, pipelined: row i+1's 8 loads are issued
// before row i's solve and stay in flight under it (partial vmcnt wait).
// Grid = N/(4*ROWS) blocks; all waves co-resident -> continuous mem/compute
// overlap instead of "load burst at wave start, compute after".
__global__ __launch_bounds__(256) void btll(
    const float* __restrict__ inputs, const float* __restrict__ targets,
    float* __restrict__ row_out, int n_rows,
    float C0, float E_off, float dE)
{
    const int lane = threadIdx.x & 63;
    const int wave = threadIdx.x >> 6;
    const int wid  = blockIdx.x * 4 + wave;
    const int base = wid * ROWS;
    if (base >= n_rows) return;

    const int o0 = lane << 2;            // 16B-aligned float offsets
    const int o1 = o0 + 256;
    const int o2 = o0 + 512;
    const bool m3 = (o0 + 768) < 1000;   // lanes 58..63 -> dup/pad
    const int o3 = m3 ? o0 + 768 : 996;  // clamp keeps addr in-bounds

    f32x4 xin[2][4], xtg[2][4];

    {   // prologue: issue row `base` (4 input + 4 target loads)
        const int r0 = (base < n_rows) ? base : n_rows - 1;
        const float* p = inputs  + (size_t)r0 * C_DIM;
        const float* q = targets + (size_t)r0 * C_DIM;
        GLOAD(xin[0][0], p + o0); GLOAD(xin[0][1], p + o1);
        GLOAD(xin[0][2], p + o2); GLOAD(xin[0][3], p + o3);
        GLOAD(xtg[0][0], q + o0); GLOAD(xtg[0][1], q + o1);
        GLOAD(xtg[0][2], q + o2); GLOAD(xtg[0][3], q + o3);
    }

    #pragma unroll
    for (int i = 0; i < ROWS; ++i) {
        const int cur = i & 1, nxt = cur ^ 1;
        const int r = base + i;

        if (i + 1 < ROWS) {
            // issue next row's loads BEFORE waiting on current row
            const int rn = (r + 1 < n_rows) ? r + 1 : n_rows - 1;
            const float* pn = inputs  + (size_t)rn * C_DIM;
            const float* qn = targets + (size_t)rn * C_DIM;
            GLOAD(xin[nxt][0], pn + o0); GLOAD(xin[nxt][1], pn + o1);
            GLOAD(xin[nxt][2], pn + o2); GLOAD(xin[nxt][3], pn + o3);
            GLOAD(xtg[nxt][0], qn + o0); GLOAD(xtg[nxt][1], qn + o1);
            GLOAD(xtg[nxt][2], qn + o2); GLOAD(xtg[nxt][3], qn + o3);
            WAIT_CUR("8", xin[cur][0], xin[cur][1], xin[cur][2], xin[cur][3],
                          xtg[cur][0], xtg[cur][1], xtg[cur][2], xtg[cur][3]);
        } else {
            WAIT_CUR("0", xin[cur][0], xin[cur][1], xin[cur][2], xin[cur][3],
                          xtg[cur][0], xtg[cur][1], xtg[cur][2], xtg[cur][3]);
        }

        f32x4 x0 = xin[cur][0], x1 = xin[cur][1], x2 = xin[cur][2], x3 = xin[cur][3];
        f32x4 t0 = xtg[cur][0], t1 = xtg[cur][1], t2 = xtg[cur][2], t3 = xtg[cur][3];
        if (!m3) {
            x3 = (f32x4){-BIG, -BIG, -BIG, -BIG};
            t3 = (f32x4){0.f, 0.f, 0.f, 0.f};
        }

        float a[16];
        a[0]=x0.x; a[1]=x0.y; a[2]=x0.z; a[3]=x0.w;
        a[4]=x1.x; a[5]=x1.y; a[6]=x1.z; a[7]=x1.w;
        a[8]=x2.x; a[9]=x2.y; a[10]=x2.z; a[11]=x2.w;
        a[12]=x3.x; a[13]=x3.y; a[14]=x3.z; a[15]=x3.w;

        // hot-class logit (targets raw one-hot {0,1}); 4-way tree; tg dies here
        float h0 = t0.x * a[0],  h1 = t0.y * a[1],  h2 = t0.z * a[2],  h3 = t0.w * a[3];
        h0 = fmaf(t1.x, a[4], h0);  h1 = fmaf(t1.y, a[5], h1);
        h2 = fmaf(t1.z, a[6], h2);  h3 = fmaf(t1.w, a[7], h3);
        h0 = fmaf(t2.x, a[8], h0);  h1 = fmaf(t2.y, a[9], h1);
        h2 = fmaf(t2.z, a[10], h2); h3 = fmaf(t2.w, a[11], h3);
        h0 = fmaf(t3.x, a[12], h0); h1 = fmaf(t3.y, a[13], h1);
        h2 = fmaf(t3.z, a[14], h2); h3 = fmaf(t3.w, a[15], h3);
        float ah = (h0 + h1) + (h2 + h3);

        float m0 = fmaxf(fmaxf(a[0], a[1]),  fmaxf(a[2], a[3]));
        float m1 = fmaxf(fmaxf(a[4], a[5]),  fmaxf(a[6], a[7]));
        float m2 = fmaxf(fmaxf(a[8], a[9]),  fmaxf(a[10], a[11]));
        float m4 = fmaxf(fmaxf(a[12], a[13]), fmaxf(a[14], a[15]));
        float mu = fmaxf(fmaxf(m0, m1), fmaxf(m2, m4));
        DPP_MAX_CHAIN(mu)
        DPP_SUM_CHAIN(ah)          // ah total valid on lane 63 (used only there)
        mu = bcast63(mu);

        float b[16];
        #pragma unroll
        for (int k = 0; k < 16; ++k) b[k] = -0.2f * (a[k] - mu);  // pad -> ~2e29

        // ---- sweep 1: FP at lam=1 ----
        float s = 0.0f;
        #pragma unroll
        for (int k = 0; k < 16; ++k) {
            float u = 1.0f + b[k];
            float u2 = u * u;
            s += frcp(u2 * u2 * u);
        }
        DPP_SUM_CHAIN(s)
        const float lam = fexp2(-0.2f * flog2(bcast63(s)));

        // ---- sweep 2: FP at lam -> w0 (below root; Newton-safe) ----
        s = 0.0f;
        #pragma unroll
        for (int k = 0; k < 16; ++k) {
            float u = fmaf(lam, b[k], 1.0f);
            float u2 = u * u;
            s += frcp(u2 * u2 * u);
        }
        DPP_SUM_CHAIN(s)
        const float w = fexp2(0.2f * flog2(bcast63(s)));

        // ---- sweep 3: merged Newton + loss sums (2nd-order corrected) ----
        float S4 = 0.0f, S5 = 0.0f, S6 = 0.0f, S9 = 0.0f, S10 = 0.0f, S11 = 0.0f;
        #pragma unroll
        for (int k = 0; k < 16; ++k) {
            float r1 = frcp(w + b[k]);
            float r2 = r1 * r1;
            float r4 = r2 * r2;
            float r5 = r4 * r1;
            float r9 = r4 * r5;
            S4  += r4;
            S5  += r5;
            S6  += r5 * r1;
            S9  += r9;
            S10 += r5 * r5;
            S11 += r9 * r2;
        }
        DPP_SUM_CHAIN(S4)
        DPP_SUM_CHAIN(S5)
        DPP_SUM_CHAIN(S6)
        DPP_SUM_CHAIN(S9)
        DPP_SUM_CHAIN(S10)
        DPP_SUM_CHAIN(S11)
        // totals on lane 63 only; final scalar math runs redundantly on all lanes

        const float hb  = -0.2f * (ah - mu);
        const float d   = (S5 - 1.0f) * 0.2f * frcp(S6);
        const float w1  = w + d;
        const float d2  = d * d;
        const float S4c = S4 + fmaf(10.0f * d2, S6,  -4.0f * d * S5);
        const float S9c = S9 + fmaf(45.0f * d2, S11, -9.0f * d * S10);
        const float rh  = frcp(w1 + hb);
        const float rh2 = rh * rh;
        const float rh4 = rh2 * rh2;
        const float loss = fmaf(-E_off, S4c, fmaf(-dE, rh4, fmaf(1.0f / 1.8f, S9c, C0)));

        if (lane == 63 && r < n_rows) row_out[r] = loss;
    }
}

__global__ __launch_bounds__(1024) void reduce_mean(
    const float* __restrict__ row_out, float* __restrict__ out, int n)
{
    __shared__ double sm[16];
    const int lane = threadIdx.x & 63;
    const int wv   = threadIdx.x >> 6;
    const float4* r4 = (const float4*)row_out;
    const int n4 = n >> 2;
    double s = 0.0;
    for (int i = threadIdx.x; i < n4; i += 1024) {
        float4 v = r4[i];
        s += (double)v.x + (double)v.y + (double)v.z + (double)v.w;
    }
    #pragma unroll
    for (int off = 32; off > 0; off >>= 1) s += __shfl_xor(s, off, 64);
    if (lane == 0) sm[wv] = s;
    __syncthreads();
    if (wv == 0) {
        double t = (lane < 16) ? sm[lane] : 0.0;
        #pragma unroll
        for (int off = 32; off > 0; off >>= 1) t += __shfl_xor(t, off, 64);
        if (lane == 0) out[0] = (float)(t / (double)n);
    }
}

extern "C" void kernel_launch(void* const* d_in, const int* in_sizes, int n_in,
                              void* d_out, int out_size, void* d_ws, size_t ws_size,
                              hipStream_t stream) {
    const float* inputs  = (const float*)d_in[0];
    const float* targets = (const float*)d_in[1];
    float* out = (float*)d_out;

    const int N = in_sizes[0] / C_DIM;
    float* row_out = (float*)d_ws;

    // Smoothed one-hot targets take 2 values; per-elem loss = F - E*r4 + r9/1.8.
    // Row sum = C0 - E_off*S4 - (E_on-E_off)*r4_hot + S9/1.8, C0 = 999*F_off + F_on.
    const double ls    = 0.05;
    const double c1g_d = 1.0 - (1000.0 / 999.0) * ls;
    const double c2_d  = ls / 999.0;
    const float  tp_on_f  = (float)c1g_d + (float)c2_d;
    const float  tp_off_f = (float)c2_d;
    const double tp_on  = (double)tp_on_f;
    const double tp_off = (double)tp_off_f;
    const double A_on  = (pow(tp_on  + 1e-8, 0.8) - 1.0) / 0.8;
    const double A_off = (pow(tp_off + 1e-8, 0.8) - 1.0) / 0.8;
    const double B_on  = pow(tp_on,  1.8);
    const double B_off = pow(tp_off, 1.8);
    const double E_on_d  = 1.25 * tp_on;
    const double E_off_d = 1.25 * tp_off;
    const double F_on_d  = tp_on  * A_on  + E_on_d  - B_on  / 1.8;
    const double F_off_d = tp_off * A_off + E_off_d - B_off / 1.8;
    const double C0_d    = (C_DIM - 1) * F_off_d + F_on_d;
    const double dE_d    = E_on_d - E_off_d;

    const int rows_per_block = 4 * ROWS;
    dim3 grid((N + rows_per_block - 1) / rows_per_block);
    btll<<<grid, 256, 0, stream>>>(inputs, targets, row_out, N,
                                   (float)C0_d, (float)E_off_d, (float)dE_d);
    reduce_mean<<<1, 1024, 0, stream>>>(row_out, out, N);
}